// Round 8
// baseline (258.904 us; speedup 1.0000x reference)
//
#include <hip/hip_runtime.h>

// Grid: 512x512 nodes, idx = row*512 + col. h = 1/511.
// m_in = [s_dst, deg_dst, s_src, deg_src, ea_x, ea_y] @ W1 -> tanh -> @ W2
// g(s)[n] = (1/deg_n) * sum_incoming(msg) + b2
//
// R7: FUSED single kernel. Each 256-thread block:
//   phase 1: grad_u/v/p for its 18x18 halo tile (324 nodes, 2 passes) -> LDS
//   phase 2: second-order g + NS combine for its 16x16 interior -> out
// Math: scalar f32 (R3-R6 evidence: pk f16/f32 both issue at ~4cy/wave on
// gfx950 = same throughput as 2cy scalar; scalar has fewest total cycles).
// tanh = med3-clamped Pade[5/4] + magic-recip + 1 Newton: 12 ops incl. acc.

#define GW  512
#define GN  (GW * GW)
#define HID 64
#define NUC 0.01f
#define TS  16            // interior tile
#define HS  18            // halo tile
#define HN  (HS * HS)     // 324

struct alignas(16) LW { float a0, a1, a2, a3, kL, kR, kU, kD, c0, c1, p0, p1; };

// tanh(t) ~= t(945+105s+s^2)/(945+420s+15s^2), s=t^2, t=med3(x,-3.8,3.8).
// recip via magic seed + 1 Newton (rel ~1.2e-3). 11 VALU ops -> th.
__device__ __forceinline__ float tanh_f(float x) {
    float t = __builtin_amdgcn_fmed3f(x, -3.8f, 3.8f);
    float s = t * t;
    float num = t * __builtin_fmaf(s, s + 105.f, 945.f);
    float den = __builtin_fmaf(s, __builtin_fmaf(s, 15.f, 420.f), 945.f);
    float r = __builtin_bit_cast(float, 0x7EF311C3u - __builtin_bit_cast(unsigned int, den));
    r = r * __builtin_fmaf(-den, r, 2.f);
    return num * r;
}

__device__ __forceinline__ void fill_lds(LW* lw, float* sb2,
                                         const float* __restrict__ W1,
                                         const float* __restrict__ b1,
                                         const float* __restrict__ W2,
                                         const float* __restrict__ b2) {
    const int t = threadIdx.x;
    if (t < HID) {
        const float H = 1.0f / 511.0f;
        float a4 = W1[4 * HID + t], a5 = W1[5 * HID + t];
        float b  = b1[t];
        LW w;
        w.a0 = W1[0 * HID + t]; w.a1 = W1[1 * HID + t];
        w.a2 = W1[2 * HID + t]; w.a3 = W1[3 * HID + t];
        w.kL = b - H * a4;   // incoming from left:  attr (-h, 0)
        w.kR = b + H * a4;   // from right: (+h, 0)
        w.kU = b - H * a5;   // from up:    (0, -h)
        w.kD = b + H * a5;   // from down:  (0, +h)
        w.c0 = W2[2 * t + 0]; w.c1 = W2[2 * t + 1];
        w.p0 = 0.f; w.p1 = 0.f;
        lw[t] = w;
    }
    if (t < 2) sb2[t] = b2[t];
}

__global__ void __launch_bounds__(256) fused_kernel(
    const float* __restrict__ fields, const float* __restrict__ degrees,
    const float* __restrict__ W1, const float* __restrict__ b1,
    const float* __restrict__ W2, const float* __restrict__ b2,
    float* __restrict__ out)
{
    __shared__ LW lw[HID];
    __shared__ float sb2[2];
    __shared__ float gt[6][HN];   // gu0 gu1 gv0 gv1 gp0 gp1 over 18x18 halo
    fill_lds(lw, sb2, W1, b1, W2, b2);
    __syncthreads();

    const int tileR = (blockIdx.x >> 5) * TS;
    const int tileC = (blockIdx.x & 31) * TS;

    // ---------- phase 1: first-order grads on the 18x18 halo ----------
    #pragma unroll
    for (int pass = 0; pass < 2; ++pass) {
        const int hi = threadIdx.x + pass * 256;
        if (hi < HN) {
            const int hr = hi / HS, hc = hi - hr * HS;
            int r = tileR - 1 + hr; r = min(max(r, 0), GW - 1);  // out-of-grid
            int c = tileC - 1 + hc; c = min(max(c, 0), GW - 1);  // never read
            const int idx = r * GW + c;
            const bool vE0 = c > 0, vE1 = c < GW - 1, vE2 = r > 0, vE3 = r < GW - 1;
            int nb[4];
            nb[0] = vE0 ? idx - 1  : idx;
            nb[1] = vE1 ? idx + 1  : idx;
            nb[2] = vE2 ? idx - GW : idx;
            nb[3] = vE3 ? idx + GW : idx;

            float s0[3], sN[4][3], dNb[4];
            #pragma unroll
            for (int f = 0; f < 3; ++f) s0[f] = fields[3 * idx + f];
            #pragma unroll
            for (int d = 0; d < 4; ++d) {
                #pragma unroll
                for (int f = 0; f < 3; ++f) sN[d][f] = fields[3 * nb[d] + f];
                dNb[d] = degrees[nb[d]];
            }
            const float dN = degrees[idx];

            float acc[4][3][2];
            #pragma unroll
            for (int d = 0; d < 4; ++d)
                #pragma unroll
                for (int f = 0; f < 3; ++f) { acc[d][f][0] = 0.f; acc[d][f][1] = 0.f; }

            #pragma unroll 2
            for (int j = 0; j < HID; ++j) {
                LW w = lw[j];
                const float dn1 = dN * w.a1;
                float hb[4];
                hb[0] = __builtin_fmaf(dNb[0], w.a3, w.kL + dn1);
                hb[1] = __builtin_fmaf(dNb[1], w.a3, w.kR + dn1);
                hb[2] = __builtin_fmaf(dNb[2], w.a3, w.kU + dn1);
                hb[3] = __builtin_fmaf(dNb[3], w.a3, w.kD + dn1);
                #pragma unroll
                for (int f = 0; f < 3; ++f) {
                    #pragma unroll
                    for (int d = 0; d < 4; ++d) {
                        float hh = __builtin_fmaf(sN[d][f], w.a2,
                                     __builtin_fmaf(s0[f], w.a0, hb[d]));
                        float th = tanh_f(hh);
                        acc[d][f][0] = __builtin_fmaf(th, w.c0, acc[d][f][0]);
                        acc[d][f][1] = __builtin_fmaf(th, w.c1, acc[d][f][1]);
                    }
                }
            }

            const float rd = __builtin_amdgcn_rcpf(dN);
            #pragma unroll
            for (int f = 0; f < 3; ++f) {
                #pragma unroll
                for (int cc = 0; cc < 2; ++cc) {
                    float s = 0.f;
                    s += vE0 ? acc[0][f][cc] : 0.f;
                    s += vE1 ? acc[1][f][cc] : 0.f;
                    s += vE2 ? acc[2][f][cc] : 0.f;
                    s += vE3 ? acc[3][f][cc] : 0.f;
                    gt[2 * f + cc][hi] = __builtin_fmaf(s, rd, sb2[cc]);
                }
            }
        }
    }
    __syncthreads();

    // ---------- phase 2: second-order g + NS combine on 16x16 interior ----------
    const int ty = threadIdx.x >> 4, tx = threadIdx.x & 15;
    const int row = tileR + ty, col = tileC + tx;
    const int idx = row * GW + col;
    const int h0 = (ty + 1) * HS + (tx + 1);
    const bool vE0 = col > 0, vE1 = col < GW - 1, vE2 = row > 0, vE3 = row < GW - 1;
    int nb[4];
    nb[0] = vE0 ? idx - 1  : idx;
    nb[1] = vE1 ? idx + 1  : idx;
    nb[2] = vE2 ? idx - GW : idx;
    nb[3] = vE3 ? idx + GW : idx;

    float s0[4], sN[4][4], dNb[4];
    #pragma unroll
    for (int f = 0; f < 4; ++f) {
        s0[f]    = gt[f][h0];
        sN[0][f] = gt[f][h0 - 1];
        sN[1][f] = gt[f][h0 + 1];
        sN[2][f] = gt[f][h0 - HS];
        sN[3][f] = gt[f][h0 + HS];
    }
    #pragma unroll
    for (int d = 0; d < 4; ++d) dNb[d] = degrees[nb[d]];
    const float dN = degrees[idx];

    float acc[4][4];
    #pragma unroll
    for (int d = 0; d < 4; ++d)
        #pragma unroll
        for (int f = 0; f < 4; ++f) acc[d][f] = 0.f;

    #pragma unroll 2
    for (int j = 0; j < HID; ++j) {
        LW w = lw[j];
        const float dn1 = dN * w.a1;
        float hb[4];
        hb[0] = __builtin_fmaf(dNb[0], w.a3, w.kL + dn1);
        hb[1] = __builtin_fmaf(dNb[1], w.a3, w.kR + dn1);
        hb[2] = __builtin_fmaf(dNb[2], w.a3, w.kU + dn1);
        hb[3] = __builtin_fmaf(dNb[3], w.a3, w.kD + dn1);
        #pragma unroll
        for (int f = 0; f < 4; ++f) {
            const float cc = (f & 1) ? w.c1 : w.c0;   // needed comp: 0,1,0,1
            #pragma unroll
            for (int d = 0; d < 4; ++d) {
                float hh = __builtin_fmaf(sN[d][f], w.a2,
                             __builtin_fmaf(s0[f], w.a0, hb[d]));
                float th = tanh_f(hh);
                acc[d][f] = __builtin_fmaf(th, cc, acc[d][f]);
            }
        }
    }

    const float rd = __builtin_amdgcn_rcpf(dN);
    float r[4];
    #pragma unroll
    for (int f = 0; f < 4; ++f) {
        float s = 0.f;
        s += vE0 ? acc[0][f] : 0.f;
        s += vE1 ? acc[1][f] : 0.f;
        s += vE2 ? acc[2][f] : 0.f;
        s += vE3 ? acc[3][f] : 0.f;
        r[f] = __builtin_fmaf(s, rd, sb2[f & 1]);
    }
    const float lap_u = r[0] + r[1];   // grad_ux[:,0] + grad_uy[:,1]
    const float lap_v = r[2] + r[3];   // grad_vx[:,0] + grad_vy[:,1]

    const float u = fields[3 * idx + 0], v = fields[3 * idx + 1];
    const float gu0 = s0[0], gu1 = s0[1], gv0 = s0[2], gv1 = s0[3];
    const float gp0 = gt[4][h0], gp1 = gt[5][h0];

    out[3 * idx + 0] = gu0 + gv1;                                    // continuity
    out[3 * idx + 1] = u * gu0 + v * gu1 + gp0 - NUC * lap_u;        // mom_x
    out[3 * idx + 2] = u * gv0 + v * gv1 + gp1 - NUC * lap_v;        // mom_y
}

extern "C" void kernel_launch(void* const* d_in, const int* in_sizes, int n_in,
                              void* d_out, int out_size, void* d_ws, size_t ws_size,
                              hipStream_t stream) {
    const float* fields  = (const float*)d_in[0];
    const float* degrees = (const float*)d_in[1];
    const float* W1 = (const float*)d_in[3];
    const float* b1 = (const float*)d_in[4];
    const float* W2 = (const float*)d_in[5];
    const float* b2 = (const float*)d_in[6];
    float* out = (float*)d_out;

    fused_kernel<<<(GW / TS) * (GW / TS), 256, 0, stream>>>(
        fields, degrees, W1, b1, W2, b2, out);
}

// Round 9
// 225.931 us; speedup vs baseline: 1.1459x; 1.1459x over previous
//
#include <hip/hip_runtime.h>

// Grid: 512x512 nodes, idx = row*512 + col. h = 1/511.
// m_in = [s_dst, deg_dst, s_src, deg_src, ea_x, ea_y] @ W1 -> tanh -> @ W2
// g(s)[n] = (1/deg_n) * sum_incoming(msg) + b2
//
// R8: consolidation at the measured VALU floor. Two kernels (fusion regressed
// in R7: 1.5x halo wave-redundancy + 1 block/SIMD barrier). SPLIT=4 hidden-dim
// slicing (R5). Scalar f32 math everywhere: R3-R6 established scalar VALU
// ~2cy/wave vs pk f16/f32 ~4cy (packing is a wash), trans ~15cy (avoided).
// tanh = med3-clamped Pade[5/4] + magic-recip + 1 Newton = 11 ops, unit = 15.

#define GW    512
#define GN    (GW * GW)
#define HID   64
#define SPLIT 4
#define JPT   (HID / SPLIT)    // 16 hidden units per thread
#define NUC   0.01f

// tanh(t) ~= t(945+105s+s^2)/(945+420s+15s^2), s=t^2, t=med3(x,-3.8,3.8).
// recip via magic seed + 1 Newton (rel ~1.2e-3). 11 VALU ops.
__device__ __forceinline__ float tanh_f(float x) {
    float t = __builtin_amdgcn_fmed3f(x, -3.8f, 3.8f);
    float s = t * t;
    float num = t * __builtin_fmaf(s, s + 105.f, 945.f);
    float den = __builtin_fmaf(s, __builtin_fmaf(s, 15.f, 420.f), 945.f);
    float r = __builtin_bit_cast(float, 0x7EF311C3u - __builtin_bit_cast(unsigned int, den));
    r = r * __builtin_fmaf(-den, r, 2.f);
    return num * r;
}

struct alignas(16) LW { float a0, a1, a2, a3, kL, kR, kU, kD, c0, c1, p0, p1; };

// Swizzled store: unit t = part*JPT + jj lands at slot jj*SPLIT + part, so a
// quad's 4 reads at step jj are consecutive structs; all 16 quads of a wave
// read the SAME 4 addresses -> broadcast, conflict-free.
__device__ __forceinline__ void fill_lds(LW* lw, float* sb2,
                                         const float* __restrict__ W1,
                                         const float* __restrict__ b1,
                                         const float* __restrict__ W2,
                                         const float* __restrict__ b2) {
    const int t = threadIdx.x;
    if (t < HID) {
        const float H = 1.0f / 511.0f;
        float a4 = W1[4 * HID + t], a5 = W1[5 * HID + t];
        float b  = b1[t];
        LW w;
        w.a0 = W1[0 * HID + t]; w.a1 = W1[1 * HID + t];
        w.a2 = W1[2 * HID + t]; w.a3 = W1[3 * HID + t];
        w.kL = b - H * a4;   // incoming from left:  attr (-h, 0)
        w.kR = b + H * a4;   // from right: (+h, 0)
        w.kU = b - H * a5;   // from up:    (0, -h)
        w.kD = b + H * a5;   // from down:  (0, +h)
        w.c0 = W2[2 * t + 0]; w.c1 = W2[2 * t + 1];
        w.p0 = 0.f; w.p1 = 0.f;
        const int slot = ((t & (JPT - 1)) * SPLIT) | (t / JPT);
        lw[slot] = w;
    }
    if (t < 2) sb2[t] = b2[t];
}

// Kernel 1: grad_u, grad_v, grad_p. SoA out: g[0]=gu0 g[1]=gu1 ... g[5]=gp1
__global__ void __launch_bounds__(256) grad3_kernel(
    const float* __restrict__ fields, const float* __restrict__ degrees,
    const float* __restrict__ W1, const float* __restrict__ b1,
    const float* __restrict__ W2, const float* __restrict__ b2,
    float* __restrict__ g)
{
    __shared__ LW lw[HID];
    __shared__ float sb2[2];
    fill_lds(lw, sb2, W1, b1, W2, b2);
    __syncthreads();

    const int gid  = blockIdx.x * 256 + threadIdx.x;
    const int idx  = gid >> 2;          // node (4 lanes per node)
    const int part = gid & 3;           // hidden-dim slice
    const int row = idx >> 9, col = idx & (GW - 1);
    const bool vE0 = col > 0, vE1 = col < GW - 1, vE2 = row > 0, vE3 = row < GW - 1;
    int nb[4];
    nb[0] = vE0 ? idx - 1  : idx;
    nb[1] = vE1 ? idx + 1  : idx;
    nb[2] = vE2 ? idx - GW : idx;
    nb[3] = vE3 ? idx + GW : idx;

    float s0[3], sN[4][3], dNb[4];
    #pragma unroll
    for (int f = 0; f < 3; ++f) s0[f] = fields[3 * idx + f];
    #pragma unroll
    for (int d = 0; d < 4; ++d) {
        #pragma unroll
        for (int f = 0; f < 3; ++f) sN[d][f] = fields[3 * nb[d] + f];
        dNb[d] = degrees[nb[d]];
    }
    const float dN = degrees[idx];

    float acc[4][3][2];
    #pragma unroll
    for (int d = 0; d < 4; ++d)
        #pragma unroll
        for (int f = 0; f < 3; ++f) { acc[d][f][0] = 0.f; acc[d][f][1] = 0.f; }

    const LW* lwp = lw + part;          // quad-consecutive slots
    #pragma unroll 2
    for (int jj = 0; jj < JPT; ++jj) {
        LW w = lwp[jj * SPLIT];
        const float dn1 = dN * w.a1;
        float hb[4];
        hb[0] = __builtin_fmaf(dNb[0], w.a3, w.kL + dn1);
        hb[1] = __builtin_fmaf(dNb[1], w.a3, w.kR + dn1);
        hb[2] = __builtin_fmaf(dNb[2], w.a3, w.kU + dn1);
        hb[3] = __builtin_fmaf(dNb[3], w.a3, w.kD + dn1);
        #pragma unroll
        for (int f = 0; f < 3; ++f) {
            #pragma unroll
            for (int d = 0; d < 4; ++d) {
                float hh = __builtin_fmaf(sN[d][f], w.a2,
                             __builtin_fmaf(s0[f], w.a0, hb[d]));
                float th = tanh_f(hh);
                acc[d][f][0] = __builtin_fmaf(th, w.c0, acc[d][f][0]);
                acc[d][f][1] = __builtin_fmaf(th, w.c1, acc[d][f][1]);
            }
        }
    }

    const float rd = __builtin_amdgcn_rcpf(dN);
    #pragma unroll
    for (int f = 0; f < 3; ++f) {
        #pragma unroll
        for (int c = 0; c < 2; ++c) {
            float s = 0.f;
            s += vE0 ? acc[0][f][c] : 0.f;
            s += vE1 ? acc[1][f][c] : 0.f;
            s += vE2 ? acc[2][f][c] : 0.f;
            s += vE3 ? acc[3][f][c] : 0.f;
            s += __shfl_xor(s, 1);
            s += __shfl_xor(s, 2);
            if (part == 0)
                g[(2 * f + c) * GN + idx] = __builtin_fmaf(s, rd, sb2[c]);
        }
    }
}

// Kernel 2: second-order g on gu0,gu1,gv0,gv1 (needed comps 0,1,0,1) + combine.
__global__ void __launch_bounds__(256) final_kernel(
    const float* __restrict__ fields, const float* __restrict__ degrees,
    const float* __restrict__ W1, const float* __restrict__ b1,
    const float* __restrict__ W2, const float* __restrict__ b2,
    const float* __restrict__ g, float* __restrict__ out)
{
    __shared__ LW lw[HID];
    __shared__ float sb2[2];
    fill_lds(lw, sb2, W1, b1, W2, b2);
    __syncthreads();

    const int gid  = blockIdx.x * 256 + threadIdx.x;
    const int idx  = gid >> 2;
    const int part = gid & 3;
    const int row = idx >> 9, col = idx & (GW - 1);
    const bool vE0 = col > 0, vE1 = col < GW - 1, vE2 = row > 0, vE3 = row < GW - 1;
    int nb[4];
    nb[0] = vE0 ? idx - 1  : idx;
    nb[1] = vE1 ? idx + 1  : idx;
    nb[2] = vE2 ? idx - GW : idx;
    nb[3] = vE3 ? idx + GW : idx;

    float s0[4], sN[4][4], dNb[4];
    #pragma unroll
    for (int f = 0; f < 4; ++f) s0[f] = g[f * GN + idx];
    #pragma unroll
    for (int d = 0; d < 4; ++d) {
        #pragma unroll
        for (int f = 0; f < 4; ++f) sN[d][f] = g[f * GN + nb[d]];
        dNb[d] = degrees[nb[d]];
    }
    const float dN = degrees[idx];

    float acc[4][4];
    #pragma unroll
    for (int d = 0; d < 4; ++d)
        #pragma unroll
        for (int f = 0; f < 4; ++f) acc[d][f] = 0.f;

    const LW* lwp = lw + part;
    #pragma unroll 2
    for (int jj = 0; jj < JPT; ++jj) {
        LW w = lwp[jj * SPLIT];
        const float dn1 = dN * w.a1;
        float hb[4];
        hb[0] = __builtin_fmaf(dNb[0], w.a3, w.kL + dn1);
        hb[1] = __builtin_fmaf(dNb[1], w.a3, w.kR + dn1);
        hb[2] = __builtin_fmaf(dNb[2], w.a3, w.kU + dn1);
        hb[3] = __builtin_fmaf(dNb[3], w.a3, w.kD + dn1);
        #pragma unroll
        for (int f = 0; f < 4; ++f) {
            const float cc = (f & 1) ? w.c1 : w.c0;   // needed comp: 0,1,0,1
            #pragma unroll
            for (int d = 0; d < 4; ++d) {
                float hh = __builtin_fmaf(sN[d][f], w.a2,
                             __builtin_fmaf(s0[f], w.a0, hb[d]));
                float th = tanh_f(hh);
                acc[d][f] = __builtin_fmaf(th, cc, acc[d][f]);
            }
        }
    }

    const float rd = __builtin_amdgcn_rcpf(dN);
    float r[4];
    #pragma unroll
    for (int f = 0; f < 4; ++f) {
        float s = 0.f;
        s += vE0 ? acc[0][f] : 0.f;
        s += vE1 ? acc[1][f] : 0.f;
        s += vE2 ? acc[2][f] : 0.f;
        s += vE3 ? acc[3][f] : 0.f;
        s += __shfl_xor(s, 1);
        s += __shfl_xor(s, 2);
        r[f] = __builtin_fmaf(s, rd, sb2[f & 1]);
    }

    if (part == 0) {
        const float lap_u = r[0] + r[1];   // grad_ux[:,0] + grad_uy[:,1]
        const float lap_v = r[2] + r[3];   // grad_vx[:,0] + grad_vy[:,1]
        const float u = fields[3 * idx + 0], v = fields[3 * idx + 1];
        const float gu0 = s0[0], gu1 = s0[1], gv0 = s0[2], gv1 = s0[3];
        const float gp0 = g[4 * GN + idx], gp1 = g[5 * GN + idx];
        out[3 * idx + 0] = gu0 + gv1;                                // continuity
        out[3 * idx + 1] = u * gu0 + v * gu1 + gp0 - NUC * lap_u;    // mom_x
        out[3 * idx + 2] = u * gv0 + v * gv1 + gp1 - NUC * lap_v;    // mom_y
    }
}

extern "C" void kernel_launch(void* const* d_in, const int* in_sizes, int n_in,
                              void* d_out, int out_size, void* d_ws, size_t ws_size,
                              hipStream_t stream) {
    const float* fields  = (const float*)d_in[0];
    const float* degrees = (const float*)d_in[1];
    const float* W1 = (const float*)d_in[3];
    const float* b1 = (const float*)d_in[4];
    const float* W2 = (const float*)d_in[5];
    const float* b2 = (const float*)d_in[6];
    float* g   = (float*)d_ws;           // 6 * GN floats = 6.3 MB scratch
    float* out = (float*)d_out;

    const int blocks = (GN * SPLIT) / 256;   // 4096
    grad3_kernel<<<blocks, 256, 0, stream>>>(fields, degrees, W1, b1, W2, b2, g);
    final_kernel<<<blocks, 256, 0, stream>>>(fields, degrees, W1, b1, W2, b2, g, out);
}

// Round 10
// 177.796 us; speedup vs baseline: 1.4562x; 1.2707x over previous
//
#include <hip/hip_runtime.h>

// Grid: 512x512 nodes, idx = row*512 + col. h = 1/511.
// m_in = [s_dst, deg_dst, s_src, deg_src, ea_x, ea_y] @ W1 -> tanh -> @ W2
// g(s)[n] = (1/deg_n) * sum_incoming(msg) + b2
//
// R9: pk-f16 (R4/R5 proven structure) with exp-trick tanh:
//   tanh(h) = 1 - 2/(1+e^{2h});  2*log2(e) folded into W1/b1 so the arg of
//   v_exp_f16 (2^x) is the MLP pre-activation directly; "1-2*" and sum_j c_j
//   folded into the epilogue: out = fma(s, -2/deg, sum_j c_j + b2).
//   Upper clamp only (lower overflow saturates to den=1 harmlessly).
//   Reciprocal: f16 magic (0x7798, R4-verified) + 1 packed Newton with
//   neg via neg_lo/neg_hi modifier. ~13 instr/pair vs R4's ~17.
// Calibration (R0-R8): ~4.5 cy/VALU-instr effective regardless of op type
// (clock throttle); instruction count per element is the only lever.

#define GW    512
#define GN    (GW * GW)
#define HID   64
#define SPLIT 4
#define JPT   (HID / SPLIT)    // 16 hidden units per thread
#define NUC   0.01f
#define FSC   2.8853900817779268f   // 2*log2(e)

typedef _Float16 h2 __attribute__((ext_vector_type(2)));

__device__ __forceinline__ float h2f(h2 x) { return __builtin_bit_cast(float, x); }
__device__ __forceinline__ h2 f2h(float x) { return __builtin_bit_cast(h2, x); }

// Inline-asm packed f16 helpers (clang won't form v_pk_* from ext_vector on
// gfx950 — R3 vs R4 evidence). Operands proxied as 32-bit floats.
__device__ __forceinline__ h2 pk_fma(h2 a, h2 b, h2 c) {
    float d, fa = h2f(a), fb = h2f(b), fc = h2f(c);
    asm("v_pk_fma_f16 %0, %1, %2, %3" : "=v"(d) : "v"(fa), "v"(fb), "v"(fc));
    return f2h(d);
}
// d = (-a)*b + c via neg modifiers (folds the Newton negate for free)
__device__ __forceinline__ h2 pk_nfma(h2 a, h2 b, h2 c) {
    float d, fa = h2f(a), fb = h2f(b), fc = h2f(c);
    asm("v_pk_fma_f16 %0, %1, %2, %3 neg_lo:[1,0,0] neg_hi:[1,0,0]"
        : "=v"(d) : "v"(fa), "v"(fb), "v"(fc));
    return f2h(d);
}
__device__ __forceinline__ h2 pk_mul(h2 a, h2 b) {
    float d, fa = h2f(a), fb = h2f(b);
    asm("v_pk_mul_f16 %0, %1, %2" : "=v"(d) : "v"(fa), "v"(fb));
    return f2h(d);
}
__device__ __forceinline__ h2 pk_add(h2 a, h2 b) {
    float d, fa = h2f(a), fb = h2f(b);
    asm("v_pk_add_f16 %0, %1, %2" : "=v"(d) : "v"(fa), "v"(fb));
    return f2h(d);
}
__device__ __forceinline__ h2 pk_min(h2 a, h2 b) {
    float d, fa = h2f(a), fb = h2f(b);
    asm("v_pk_min_f16 %0, %1, %2" : "=v"(d) : "v"(fa), "v"(fb));
    return f2h(d);
}

__device__ __forceinline__ h2 h2c(float x) {
    h2 r; r.x = (_Float16)x; r.y = (_Float16)x; return r;
}
__device__ __forceinline__ h2 h2p(float a, float b) {
    h2 r; r.x = (_Float16)a; r.y = (_Float16)b; return r;
}

// r ~= 1/(1+e), e = 2^hc, hc pre-clamped so den in [1, 4097] (magic-safe).
// Returns r; tanh = 1 - 2r handled in epilogue.
__device__ __forceinline__ h2 sigr(h2 hc, h2 one, h2 two) {
    h2 e   = __builtin_elementwise_exp2(hc);     // 2x v_exp_f16 (hazard-safe)
    h2 den = pk_add(e, one);
    unsigned int db = __builtin_bit_cast(unsigned int, den);
    h2 r0  = __builtin_bit_cast(h2, 0x77987798u - db);   // magic seed
    return pk_mul(r0, pk_nfma(den, r0, two));            // 1 Newton
}

struct alignas(16) LWH {           // 32 B per hidden unit, broadcast pairs
    h2 a0, a1, a2, a3;             // FSC-scaled W1 rows 0..3 (dup both halves)
    h2 kLR, kUD;                   // FSC*(b1 + ea.W1[4:6]) per incoming dir
    h2 c0, c1;                     // W2 row raw (dup)
};

// Swizzle: unit t = part*JPT + jj -> slot jj*SPLIT + part (quad-consecutive,
// broadcast-conflict-free). Also computes Cb[c] = sum_j W2[j][c] + b2[c].
__device__ __forceinline__ void fill_lds(LWH* lw, float* sCb,
                                         const float* __restrict__ W1,
                                         const float* __restrict__ b1,
                                         const float* __restrict__ W2,
                                         const float* __restrict__ b2) {
    const int t = threadIdx.x;
    if (t < HID) {                 // threads 0..63 == wave 0 exactly
        const float H = 1.0f / 511.0f;
        float a4 = W1[4 * HID + t], a5 = W1[5 * HID + t];
        float b  = b1[t];
        float c0f = W2[2 * t + 0], c1f = W2[2 * t + 1];
        LWH w;
        w.a0 = h2c(FSC * W1[0 * HID + t]); w.a1 = h2c(FSC * W1[1 * HID + t]);
        w.a2 = h2c(FSC * W1[2 * HID + t]); w.a3 = h2c(FSC * W1[3 * HID + t]);
        w.kLR = h2p(FSC * (b - H * a4), FSC * (b + H * a4));
        w.kUD = h2p(FSC * (b - H * a5), FSC * (b + H * a5));
        w.c0 = h2c(c0f);  w.c1 = h2c(c1f);
        const int slot = ((t & (JPT - 1)) * SPLIT) | (t / JPT);
        lw[slot] = w;
        // wave-0 butterfly: C_c = sum over all 64 units of W2[:,c]
        float v0 = c0f, v1 = c1f;
        #pragma unroll
        for (int off = 1; off < 64; off <<= 1) {
            v0 += __shfl_xor(v0, off);
            v1 += __shfl_xor(v1, off);
        }
        if (t == 0) { sCb[0] = v0 + b2[0]; sCb[1] = v1 + b2[1]; }
    }
}

// Kernel 1: grad_u, grad_v, grad_p. SoA out: g[0]=gu0 g[1]=gu1 ... g[5]=gp1
__global__ void __launch_bounds__(256) grad3_kernel(
    const float* __restrict__ fields, const float* __restrict__ degrees,
    const float* __restrict__ W1, const float* __restrict__ b1,
    const float* __restrict__ W2, const float* __restrict__ b2,
    float* __restrict__ g)
{
    __shared__ LWH lw[HID];
    __shared__ float sCb[2];
    fill_lds(lw, sCb, W1, b1, W2, b2);
    __syncthreads();

    const int gid  = blockIdx.x * 256 + threadIdx.x;
    const int idx  = gid >> 2;          // node (4 lanes per node)
    const int part = gid & 3;           // hidden-dim slice
    const int row = idx >> 9, col = idx & (GW - 1);
    const bool vE0 = col > 0, vE1 = col < GW - 1, vE2 = row > 0, vE3 = row < GW - 1;
    int nb[4];
    nb[0] = vE0 ? idx - 1  : idx;
    nb[1] = vE1 ? idx + 1  : idx;
    nb[2] = vE2 ? idx - GW : idx;
    nb[3] = vE3 ? idx + GW : idx;

    const h2 one = h2c(1.f), two = h2c(2.f), hcl = h2c(12.0f);

    h2 s0h[3];
    #pragma unroll
    for (int f = 0; f < 3; ++f) s0h[f] = h2c(fields[3 * idx + f]);
    h2 sN2[2][3];                       // [pair LR/UD][field]
    #pragma unroll
    for (int f = 0; f < 3; ++f) {
        sN2[0][f] = h2p(fields[3 * nb[0] + f], fields[3 * nb[1] + f]);
        sN2[1][f] = h2p(fields[3 * nb[2] + f], fields[3 * nb[3] + f]);
    }
    h2 dnbLR = h2p(degrees[nb[0]], degrees[nb[1]]);
    h2 dnbUD = h2p(degrees[nb[2]], degrees[nb[3]]);
    const float dN = degrees[idx];
    const h2 dNh = h2c(dN);

    h2 acc[2][3][2];                    // [pair][field][W2 comp], holds sum c*r
    #pragma unroll
    for (int dp = 0; dp < 2; ++dp)
        #pragma unroll
        for (int f = 0; f < 3; ++f) { acc[dp][f][0] = h2c(0.f); acc[dp][f][1] = h2c(0.f); }

    const LWH* lwp = lw + part;         // quad-consecutive slots
    #pragma unroll 2
    for (int jj = 0; jj < JPT; ++jj) {
        LWH w = lwp[jj * SPLIT];
        h2 dn1 = pk_mul(dNh, w.a1);
        h2 hb[2];
        hb[0] = pk_fma(dnbLR, w.a3, pk_add(w.kLR, dn1));
        hb[1] = pk_fma(dnbUD, w.a3, pk_add(w.kUD, dn1));
        #pragma unroll
        for (int f = 0; f < 3; ++f) {
            #pragma unroll
            for (int dp = 0; dp < 2; ++dp) {
                h2 hh = pk_fma(sN2[dp][f], w.a2, pk_fma(s0h[f], w.a0, hb[dp]));
                h2 r  = sigr(pk_min(hcl, hh), one, two);
                acc[dp][f][0] = pk_fma(r, w.c0, acc[dp][f][0]);
                acc[dp][f][1] = pk_fma(r, w.c1, acc[dp][f][1]);
            }
        }
    }

    const float m2rd = -2.0f * __builtin_amdgcn_rcpf(dN);
    #pragma unroll
    for (int f = 0; f < 3; ++f) {
        #pragma unroll
        for (int c = 0; c < 2; ++c) {
            float s = 0.f;
            s += vE0 ? (float)acc[0][f][c].x : 0.f;
            s += vE1 ? (float)acc[0][f][c].y : 0.f;
            s += vE2 ? (float)acc[1][f][c].x : 0.f;
            s += vE3 ? (float)acc[1][f][c].y : 0.f;
            s += __shfl_xor(s, 1);
            s += __shfl_xor(s, 2);
            if (part == 0)   // sum_d valid = dN, so (dN*C - 2s)/dN + b2 = fma
                g[(2 * f + c) * GN + idx] = __builtin_fmaf(s, m2rd, sCb[c]);
        }
    }
}

// Kernel 2: second-order g on gu0,gu1,gv0,gv1 (needed comps 0,1,0,1) + combine.
__global__ void __launch_bounds__(256) final_kernel(
    const float* __restrict__ fields, const float* __restrict__ degrees,
    const float* __restrict__ W1, const float* __restrict__ b1,
    const float* __restrict__ W2, const float* __restrict__ b2,
    const float* __restrict__ g, float* __restrict__ out)
{
    __shared__ LWH lw[HID];
    __shared__ float sCb[2];
    fill_lds(lw, sCb, W1, b1, W2, b2);
    __syncthreads();

    const int gid  = blockIdx.x * 256 + threadIdx.x;
    const int idx  = gid >> 2;
    const int part = gid & 3;
    const int row = idx >> 9, col = idx & (GW - 1);
    const bool vE0 = col > 0, vE1 = col < GW - 1, vE2 = row > 0, vE3 = row < GW - 1;
    int nb[4];
    nb[0] = vE0 ? idx - 1  : idx;
    nb[1] = vE1 ? idx + 1  : idx;
    nb[2] = vE2 ? idx - GW : idx;
    nb[3] = vE3 ? idx + GW : idx;

    const h2 one = h2c(1.f), two = h2c(2.f), hcl = h2c(12.0f);

    float s0[4];
    #pragma unroll
    for (int f = 0; f < 4; ++f) s0[f] = g[f * GN + idx];
    h2 s0h[4];
    #pragma unroll
    for (int f = 0; f < 4; ++f) s0h[f] = h2c(s0[f]);
    h2 sN2[2][4];
    #pragma unroll
    for (int f = 0; f < 4; ++f) {
        sN2[0][f] = h2p(g[f * GN + nb[0]], g[f * GN + nb[1]]);
        sN2[1][f] = h2p(g[f * GN + nb[2]], g[f * GN + nb[3]]);
    }
    h2 dnbLR = h2p(degrees[nb[0]], degrees[nb[1]]);
    h2 dnbUD = h2p(degrees[nb[2]], degrees[nb[3]]);
    const float dN = degrees[idx];
    const h2 dNh = h2c(dN);

    h2 acc[2][4];                       // [pair][field], holds sum c*r
    #pragma unroll
    for (int dp = 0; dp < 2; ++dp)
        #pragma unroll
        for (int f = 0; f < 4; ++f) acc[dp][f] = h2c(0.f);

    const LWH* lwp = lw + part;
    #pragma unroll 2
    for (int jj = 0; jj < JPT; ++jj) {
        LWH w = lwp[jj * SPLIT];
        h2 dn1 = pk_mul(dNh, w.a1);
        h2 hb[2];
        hb[0] = pk_fma(dnbLR, w.a3, pk_add(w.kLR, dn1));
        hb[1] = pk_fma(dnbUD, w.a3, pk_add(w.kUD, dn1));
        #pragma unroll
        for (int f = 0; f < 4; ++f) {
            h2 cc = (f & 1) ? w.c1 : w.c0;   // needed comp: 0,1,0,1
            #pragma unroll
            for (int dp = 0; dp < 2; ++dp) {
                h2 hh = pk_fma(sN2[dp][f], w.a2, pk_fma(s0h[f], w.a0, hb[dp]));
                h2 r  = sigr(pk_min(hcl, hh), one, two);
                acc[dp][f] = pk_fma(r, cc, acc[dp][f]);
            }
        }
    }

    const float m2rd = -2.0f * __builtin_amdgcn_rcpf(dN);
    float r[4];
    #pragma unroll
    for (int f = 0; f < 4; ++f) {
        float s = 0.f;
        s += vE0 ? (float)acc[0][f].x : 0.f;
        s += vE1 ? (float)acc[0][f].y : 0.f;
        s += vE2 ? (float)acc[1][f].x : 0.f;
        s += vE3 ? (float)acc[1][f].y : 0.f;
        s += __shfl_xor(s, 1);
        s += __shfl_xor(s, 2);
        r[f] = __builtin_fmaf(s, m2rd, sCb[f & 1]);
    }

    if (part == 0) {
        const float lap_u = r[0] + r[1];   // grad_ux[:,0] + grad_uy[:,1]
        const float lap_v = r[2] + r[3];   // grad_vx[:,0] + grad_vy[:,1]
        const float u = fields[3 * idx + 0], v = fields[3 * idx + 1];
        const float gu0 = s0[0], gu1 = s0[1], gv0 = s0[2], gv1 = s0[3];
        const float gp0 = g[4 * GN + idx], gp1 = g[5 * GN + idx];
        out[3 * idx + 0] = gu0 + gv1;                                // continuity
        out[3 * idx + 1] = u * gu0 + v * gu1 + gp0 - NUC * lap_u;    // mom_x
        out[3 * idx + 2] = u * gv0 + v * gv1 + gp1 - NUC * lap_v;    // mom_y
    }
}

extern "C" void kernel_launch(void* const* d_in, const int* in_sizes, int n_in,
                              void* d_out, int out_size, void* d_ws, size_t ws_size,
                              hipStream_t stream) {
    const float* fields  = (const float*)d_in[0];
    const float* degrees = (const float*)d_in[1];
    const float* W1 = (const float*)d_in[3];
    const float* b1 = (const float*)d_in[4];
    const float* W2 = (const float*)d_in[5];
    const float* b2 = (const float*)d_in[6];
    float* g   = (float*)d_ws;           // 6 * GN floats = 6.3 MB scratch
    float* out = (float*)d_out;

    const int blocks = (GN * SPLIT) / 256;   // 4096
    grad3_kernel<<<blocks, 256, 0, stream>>>(fields, degrees, W1, b1, W2, b2, g);
    final_kernel<<<blocks, 256, 0, stream>>>(fields, degrees, W1, b1, W2, b2, g, out);
}

// Round 11
// 161.061 us; speedup vs baseline: 1.6075x; 1.1039x over previous
//
#include <hip/hip_runtime.h>

// Grid: 512x512 nodes, idx = row*512 + col. h = 1/511.
// m_in = [s_dst, deg_dst, s_src, deg_src, ea_x, ea_y] @ W1 -> tanh -> @ W2
// g(s)[n] = (1/deg_n) * sum_incoming(msg) + b2
//
// R10: final_kernel's MLP output enters the result ONLY via lap_u/lap_v
// scaled by NU=0.01 (continuity & advection use first-order g directly), so
// its activation can be sloppy: clamped Hermite cubic t*(0.75-0.0625 t^2),
// t=clamp(h,+-2) — max err ~0.1 vs tanh -> <=0.006 on output. No trans, no
// division: 8 pk-instr/pair vs R9's 10+2trans (34 cy vs 66 at the measured
// 4cy/VALU, 16cy/trans rates). grad3 (undamped output) keeps R9's verified
// exp-sigmoid: exp-trick tanh, FSC folded into weights, magic recip+Newton.

#define GW    512
#define GN    (GW * GW)
#define HID   64
#define SPLIT 4
#define JPT   (HID / SPLIT)    // 16 hidden units per thread
#define NUC   0.01f
#define FSC   2.8853900817779268f   // 2*log2(e)

typedef _Float16 h2 __attribute__((ext_vector_type(2)));

__device__ __forceinline__ float h2f(h2 x) { return __builtin_bit_cast(float, x); }
__device__ __forceinline__ h2 f2h(float x) { return __builtin_bit_cast(h2, x); }

// Inline-asm packed f16 helpers (clang won't form v_pk_* from ext_vector on
// gfx950 — R3 vs R4 evidence). Operands proxied as 32-bit floats.
__device__ __forceinline__ h2 pk_fma(h2 a, h2 b, h2 c) {
    float d, fa = h2f(a), fb = h2f(b), fc = h2f(c);
    asm("v_pk_fma_f16 %0, %1, %2, %3" : "=v"(d) : "v"(fa), "v"(fb), "v"(fc));
    return f2h(d);
}
// d = (-a)*b + c via neg modifiers
__device__ __forceinline__ h2 pk_nfma(h2 a, h2 b, h2 c) {
    float d, fa = h2f(a), fb = h2f(b), fc = h2f(c);
    asm("v_pk_fma_f16 %0, %1, %2, %3 neg_lo:[1,0,0] neg_hi:[1,0,0]"
        : "=v"(d) : "v"(fa), "v"(fb), "v"(fc));
    return f2h(d);
}
__device__ __forceinline__ h2 pk_mul(h2 a, h2 b) {
    float d, fa = h2f(a), fb = h2f(b);
    asm("v_pk_mul_f16 %0, %1, %2" : "=v"(d) : "v"(fa), "v"(fb));
    return f2h(d);
}
__device__ __forceinline__ h2 pk_add(h2 a, h2 b) {
    float d, fa = h2f(a), fb = h2f(b);
    asm("v_pk_add_f16 %0, %1, %2" : "=v"(d) : "v"(fa), "v"(fb));
    return f2h(d);
}
__device__ __forceinline__ h2 pk_min(h2 a, h2 b) {
    float d, fa = h2f(a), fb = h2f(b);
    asm("v_pk_min_f16 %0, %1, %2" : "=v"(d) : "v"(fa), "v"(fb));
    return f2h(d);
}
__device__ __forceinline__ h2 pk_max(h2 a, h2 b) {
    float d, fa = h2f(a), fb = h2f(b);
    asm("v_pk_max_f16 %0, %1, %2" : "=v"(d) : "v"(fa), "v"(fb));
    return f2h(d);
}

__device__ __forceinline__ h2 h2c(float x) {
    h2 r; r.x = (_Float16)x; r.y = (_Float16)x; return r;
}
__device__ __forceinline__ h2 h2p(float a, float b) {
    h2 r; r.x = (_Float16)a; r.y = (_Float16)b; return r;
}

// r ~= 1/(1+e), e = 2^hc, hc pre-clamped so den in [1, 4097] (magic-safe).
__device__ __forceinline__ h2 sigr(h2 hc, h2 one, h2 two) {
    h2 e   = __builtin_elementwise_exp2(hc);     // 2x v_exp_f16
    h2 den = pk_add(e, one);
    unsigned int db = __builtin_bit_cast(unsigned int, den);
    h2 r0  = __builtin_bit_cast(h2, 0x77987798u - db);   // magic seed
    return pk_mul(r0, pk_nfma(den, r0, two));            // 1 Newton
}

struct alignas(16) LWH {           // 32 B per hidden unit, broadcast pairs
    h2 a0, a1, a2, a3;             // W1 rows 0..3 (dup both halves)
    h2 kLR, kUD;                   // (b1 + ea.W1[4:6]) per incoming dir
    h2 c0, c1;                     // W2 row (dup)
};

// Swizzle: unit t = part*JPT + jj -> slot jj*SPLIT + part (quad-consecutive,
// broadcast-conflict-free). scale=FSC for grad3 (exp-trick), 1 for final.
// Also computes sCb[c] = sum_j W2[j][c] + b2[c] (used by grad3 epilogue only).
__device__ __forceinline__ void fill_lds(LWH* lw, float* sCb, float scale,
                                         const float* __restrict__ W1,
                                         const float* __restrict__ b1,
                                         const float* __restrict__ W2,
                                         const float* __restrict__ b2) {
    const int t = threadIdx.x;
    if (t < HID) {                 // threads 0..63 == wave 0 exactly
        const float H = 1.0f / 511.0f;
        float a4 = W1[4 * HID + t], a5 = W1[5 * HID + t];
        float b  = b1[t];
        float c0f = W2[2 * t + 0], c1f = W2[2 * t + 1];
        LWH w;
        w.a0 = h2c(scale * W1[0 * HID + t]); w.a1 = h2c(scale * W1[1 * HID + t]);
        w.a2 = h2c(scale * W1[2 * HID + t]); w.a3 = h2c(scale * W1[3 * HID + t]);
        w.kLR = h2p(scale * (b - H * a4), scale * (b + H * a4));
        w.kUD = h2p(scale * (b - H * a5), scale * (b + H * a5));
        w.c0 = h2c(c0f);  w.c1 = h2c(c1f);
        const int slot = ((t & (JPT - 1)) * SPLIT) | (t / JPT);
        lw[slot] = w;
        float v0 = c0f, v1 = c1f;
        #pragma unroll
        for (int off = 1; off < 64; off <<= 1) {
            v0 += __shfl_xor(v0, off);
            v1 += __shfl_xor(v1, off);
        }
        if (t == 0) { sCb[0] = v0 + b2[0]; sCb[1] = v1 + b2[1]; }
    }
}

// Kernel 1: grad_u, grad_v, grad_p (UNDAMPED outputs -> accurate exp path).
// SoA out: g[0]=gu0 g[1]=gu1 ... g[5]=gp1
__global__ void __launch_bounds__(256) grad3_kernel(
    const float* __restrict__ fields, const float* __restrict__ degrees,
    const float* __restrict__ W1, const float* __restrict__ b1,
    const float* __restrict__ W2, const float* __restrict__ b2,
    float* __restrict__ g)
{
    __shared__ LWH lw[HID];
    __shared__ float sCb[2];
    fill_lds(lw, sCb, FSC, W1, b1, W2, b2);
    __syncthreads();

    const int gid  = blockIdx.x * 256 + threadIdx.x;
    const int idx  = gid >> 2;          // node (4 lanes per node)
    const int part = gid & 3;           // hidden-dim slice
    const int row = idx >> 9, col = idx & (GW - 1);
    const bool vE0 = col > 0, vE1 = col < GW - 1, vE2 = row > 0, vE3 = row < GW - 1;
    int nb[4];
    nb[0] = vE0 ? idx - 1  : idx;
    nb[1] = vE1 ? idx + 1  : idx;
    nb[2] = vE2 ? idx - GW : idx;
    nb[3] = vE3 ? idx + GW : idx;

    const h2 one = h2c(1.f), two = h2c(2.f), hcl = h2c(12.0f);

    h2 s0h[3];
    #pragma unroll
    for (int f = 0; f < 3; ++f) s0h[f] = h2c(fields[3 * idx + f]);
    h2 sN2[2][3];                       // [pair LR/UD][field]
    #pragma unroll
    for (int f = 0; f < 3; ++f) {
        sN2[0][f] = h2p(fields[3 * nb[0] + f], fields[3 * nb[1] + f]);
        sN2[1][f] = h2p(fields[3 * nb[2] + f], fields[3 * nb[3] + f]);
    }
    h2 dnbLR = h2p(degrees[nb[0]], degrees[nb[1]]);
    h2 dnbUD = h2p(degrees[nb[2]], degrees[nb[3]]);
    const float dN = degrees[idx];
    const h2 dNh = h2c(dN);

    h2 acc[2][3][2];                    // [pair][field][W2 comp], sum c*r
    #pragma unroll
    for (int dp = 0; dp < 2; ++dp)
        #pragma unroll
        for (int f = 0; f < 3; ++f) { acc[dp][f][0] = h2c(0.f); acc[dp][f][1] = h2c(0.f); }

    const LWH* lwp = lw + part;
    #pragma unroll 2
    for (int jj = 0; jj < JPT; ++jj) {
        LWH w = lwp[jj * SPLIT];
        h2 dn1 = pk_mul(dNh, w.a1);
        h2 hb[2];
        hb[0] = pk_fma(dnbLR, w.a3, pk_add(w.kLR, dn1));
        hb[1] = pk_fma(dnbUD, w.a3, pk_add(w.kUD, dn1));
        #pragma unroll
        for (int f = 0; f < 3; ++f) {
            #pragma unroll
            for (int dp = 0; dp < 2; ++dp) {
                h2 hh = pk_fma(sN2[dp][f], w.a2, pk_fma(s0h[f], w.a0, hb[dp]));
                h2 r  = sigr(pk_min(hcl, hh), one, two);
                acc[dp][f][0] = pk_fma(r, w.c0, acc[dp][f][0]);
                acc[dp][f][1] = pk_fma(r, w.c1, acc[dp][f][1]);
            }
        }
    }

    const float m2rd = -2.0f * __builtin_amdgcn_rcpf(dN);
    #pragma unroll
    for (int f = 0; f < 3; ++f) {
        #pragma unroll
        for (int c = 0; c < 2; ++c) {
            float s = 0.f;
            s += vE0 ? (float)acc[0][f][c].x : 0.f;
            s += vE1 ? (float)acc[0][f][c].y : 0.f;
            s += vE2 ? (float)acc[1][f][c].x : 0.f;
            s += vE3 ? (float)acc[1][f][c].y : 0.f;
            s += __shfl_xor(s, 1);
            s += __shfl_xor(s, 2);
            if (part == 0)
                g[(2 * f + c) * GN + idx] = __builtin_fmaf(s, m2rd, sCb[c]);
        }
    }
}

// Kernel 2: second-order g (outputs damped by NU=0.01 -> cubic activation)
// + NS combine.
__global__ void __launch_bounds__(256) final_kernel(
    const float* __restrict__ fields, const float* __restrict__ degrees,
    const float* __restrict__ W1, const float* __restrict__ b1,
    const float* __restrict__ W2, const float* __restrict__ b2,
    const float* __restrict__ g, float* __restrict__ out)
{
    __shared__ LWH lw[HID];
    __shared__ float sCb[2];
    fill_lds(lw, sCb, 1.0f, W1, b1, W2, b2);   // raw weights (no FSC)
    __syncthreads();

    const int gid  = blockIdx.x * 256 + threadIdx.x;
    const int idx  = gid >> 2;
    const int part = gid & 3;
    const int row = idx >> 9, col = idx & (GW - 1);
    const bool vE0 = col > 0, vE1 = col < GW - 1, vE2 = row > 0, vE3 = row < GW - 1;
    int nb[4];
    nb[0] = vE0 ? idx - 1  : idx;
    nb[1] = vE1 ? idx + 1  : idx;
    nb[2] = vE2 ? idx - GW : idx;
    nb[3] = vE3 ? idx + GW : idx;

    // cubic tanh: t = clamp(h,+-2); th = t*(0.75 - 0.0625 t^2)
    const h2 cP = h2c(2.0f), cM = h2c(-2.0f), cA = h2c(0.75f), cB = h2c(-0.0625f);

    float s0[4];
    #pragma unroll
    for (int f = 0; f < 4; ++f) s0[f] = g[f * GN + idx];
    h2 s0h[4];
    #pragma unroll
    for (int f = 0; f < 4; ++f) s0h[f] = h2c(s0[f]);
    h2 sN2[2][4];
    #pragma unroll
    for (int f = 0; f < 4; ++f) {
        sN2[0][f] = h2p(g[f * GN + nb[0]], g[f * GN + nb[1]]);
        sN2[1][f] = h2p(g[f * GN + nb[2]], g[f * GN + nb[3]]);
    }
    h2 dnbLR = h2p(degrees[nb[0]], degrees[nb[1]]);
    h2 dnbUD = h2p(degrees[nb[2]], degrees[nb[3]]);
    const float dN = degrees[idx];
    const h2 dNh = h2c(dN);

    h2 acc[2][4];                       // [pair][field], sum c*th
    #pragma unroll
    for (int dp = 0; dp < 2; ++dp)
        #pragma unroll
        for (int f = 0; f < 4; ++f) acc[dp][f] = h2c(0.f);

    const LWH* lwp = lw + part;
    #pragma unroll 2
    for (int jj = 0; jj < JPT; ++jj) {
        LWH w = lwp[jj * SPLIT];
        h2 dn1 = pk_mul(dNh, w.a1);
        h2 hb[2];
        hb[0] = pk_fma(dnbLR, w.a3, pk_add(w.kLR, dn1));
        hb[1] = pk_fma(dnbUD, w.a3, pk_add(w.kUD, dn1));
        #pragma unroll
        for (int f = 0; f < 4; ++f) {
            h2 cc = (f & 1) ? w.c1 : w.c0;   // needed comp: 0,1,0,1
            #pragma unroll
            for (int dp = 0; dp < 2; ++dp) {
                h2 hh = pk_fma(sN2[dp][f], w.a2, pk_fma(s0h[f], w.a0, hb[dp]));
                h2 t  = pk_min(cP, pk_max(cM, hh));
                h2 th = pk_mul(t, pk_fma(pk_mul(t, t), cB, cA));
                acc[dp][f] = pk_fma(th, cc, acc[dp][f]);
            }
        }
    }

    const float rd = __builtin_amdgcn_rcpf(dN);
    float r[4];
    #pragma unroll
    for (int f = 0; f < 4; ++f) {
        float s = 0.f;
        s += vE0 ? (float)acc[0][f].x : 0.f;
        s += vE1 ? (float)acc[0][f].y : 0.f;
        s += vE2 ? (float)acc[1][f].x : 0.f;
        s += vE3 ? (float)acc[1][f].y : 0.f;
        s += __shfl_xor(s, 1);
        s += __shfl_xor(s, 2);
        r[f] = __builtin_fmaf(s, rd, b2[f & 1]);
    }

    if (part == 0) {
        const float lap_u = r[0] + r[1];   // grad_ux[:,0] + grad_uy[:,1]
        const float lap_v = r[2] + r[3];   // grad_vx[:,0] + grad_vy[:,1]
        const float u = fields[3 * idx + 0], v = fields[3 * idx + 1];
        const float gu0 = s0[0], gu1 = s0[1], gv0 = s0[2], gv1 = s0[3];
        const float gp0 = g[4 * GN + idx], gp1 = g[5 * GN + idx];
        out[3 * idx + 0] = gu0 + gv1;                                // continuity
        out[3 * idx + 1] = u * gu0 + v * gu1 + gp0 - NUC * lap_u;    // mom_x
        out[3 * idx + 2] = u * gv0 + v * gv1 + gp1 - NUC * lap_v;    // mom_y
    }
}

extern "C" void kernel_launch(void* const* d_in, const int* in_sizes, int n_in,
                              void* d_out, int out_size, void* d_ws, size_t ws_size,
                              hipStream_t stream) {
    const float* fields  = (const float*)d_in[0];
    const float* degrees = (const float*)d_in[1];
    const float* W1 = (const float*)d_in[3];
    const float* b1 = (const float*)d_in[4];
    const float* W2 = (const float*)d_in[5];
    const float* b2 = (const float*)d_in[6];
    float* g   = (float*)d_ws;           // 6 * GN floats = 6.3 MB scratch
    float* out = (float*)d_out;

    const int blocks = (GN * SPLIT) / 256;   // 4096
    grad3_kernel<<<blocks, 256, 0, stream>>>(fields, degrees, W1, b1, W2, b2, g);
    final_kernel<<<blocks, 256, 0, stream>>>(fields, degrees, W1, b1, W2, b2, g, out);
}

// Round 12
// 160.320 us; speedup vs baseline: 1.6149x; 1.0046x over previous
//
#include <hip/hip_runtime.h>

// Grid: 512x512 nodes, idx = row*512 + col. h = 1/511.
// m_in = [s_dst, deg_dst, s_src, deg_src, ea_x, ea_y] @ W1 -> tanh -> @ W2
// g(s)[n] = (1/deg_n) * sum_incoming(msg) + b2
//
// R11: grad3 loses its last transcendentals. Activation ladder (all pk f16,
// inline asm; measured rates: VALU 4cy/wave-instr, trans 16cy):
//   grad3  (undamped outputs): lambda-centered Pade[3/2]
//          tanh(x) ~= 0.9873 * x(27+x^2)/(27+9x^2), clamp +-3.4, err ~0.013;
//          lambda folded into the W2 copy in LDS. 14 instr/pair = 56cy vs
//          exp-sigmoid's 68cy.
//   final  (outputs damped by NU=0.01): Hermite cubic t(0.75-0.0625t^2),
//          t=clamp(h,+-2), err ~0.1 -> <=0.006 on output. 8 instr/pair.
// Division-free: f16 magic recip (0x7798) + 1 packed Newton, neg folded via
// neg_lo/neg_hi. SPLIT=4 hidden-dim slicing, swizzled broadcast LDS weights.

#define GW    512
#define GN    (GW * GW)
#define HID   64
#define SPLIT 4
#define JPT   (HID / SPLIT)    // 16 hidden units per thread
#define NUC   0.01f
#define LAM   0.9873f          // Pade error-centering, folded into c0/c1

typedef _Float16 h2 __attribute__((ext_vector_type(2)));

__device__ __forceinline__ float h2f(h2 x) { return __builtin_bit_cast(float, x); }
__device__ __forceinline__ h2 f2h(float x) { return __builtin_bit_cast(h2, x); }

// Inline-asm packed f16 helpers (clang won't form v_pk_* from ext_vector on
// gfx950 — R3 vs R4 evidence). Operands proxied as 32-bit floats.
__device__ __forceinline__ h2 pk_fma(h2 a, h2 b, h2 c) {
    float d, fa = h2f(a), fb = h2f(b), fc = h2f(c);
    asm("v_pk_fma_f16 %0, %1, %2, %3" : "=v"(d) : "v"(fa), "v"(fb), "v"(fc));
    return f2h(d);
}
// d = (-a)*b + c via neg modifiers
__device__ __forceinline__ h2 pk_nfma(h2 a, h2 b, h2 c) {
    float d, fa = h2f(a), fb = h2f(b), fc = h2f(c);
    asm("v_pk_fma_f16 %0, %1, %2, %3 neg_lo:[1,0,0] neg_hi:[1,0,0]"
        : "=v"(d) : "v"(fa), "v"(fb), "v"(fc));
    return f2h(d);
}
__device__ __forceinline__ h2 pk_mul(h2 a, h2 b) {
    float d, fa = h2f(a), fb = h2f(b);
    asm("v_pk_mul_f16 %0, %1, %2" : "=v"(d) : "v"(fa), "v"(fb));
    return f2h(d);
}
__device__ __forceinline__ h2 pk_add(h2 a, h2 b) {
    float d, fa = h2f(a), fb = h2f(b);
    asm("v_pk_add_f16 %0, %1, %2" : "=v"(d) : "v"(fa), "v"(fb));
    return f2h(d);
}
__device__ __forceinline__ h2 pk_min(h2 a, h2 b) {
    float d, fa = h2f(a), fb = h2f(b);
    asm("v_pk_min_f16 %0, %1, %2" : "=v"(d) : "v"(fa), "v"(fb));
    return f2h(d);
}
__device__ __forceinline__ h2 pk_max(h2 a, h2 b) {
    float d, fa = h2f(a), fb = h2f(b);
    asm("v_pk_max_f16 %0, %1, %2" : "=v"(d) : "v"(fa), "v"(fb));
    return f2h(d);
}

__device__ __forceinline__ h2 h2c(float x) {
    h2 r; r.x = (_Float16)x; r.y = (_Float16)x; return r;
}
__device__ __forceinline__ h2 h2p(float a, float b) {
    h2 r; r.x = (_Float16)a; r.y = (_Float16)b; return r;
}

struct alignas(16) LWH {           // 32 B per hidden unit, broadcast pairs
    h2 a0, a1, a2, a3;             // W1 rows 0..3 (dup both halves)
    h2 kLR, kUD;                   // (b1 + ea.W1[4:6]) per incoming dir
    h2 c0, c1;                     // cscale * W2 row (dup)
};

// Swizzle: unit t = part*JPT + jj -> slot jj*SPLIT + part (quad-consecutive,
// broadcast-conflict-free). cscale = LAM for grad3's Pade centering, 1 else.
__device__ __forceinline__ void fill_lds(LWH* lw, float cscale,
                                         const float* __restrict__ W1,
                                         const float* __restrict__ b1,
                                         const float* __restrict__ W2,
                                         const float* __restrict__ b2) {
    const int t = threadIdx.x;
    if (t < HID) {
        const float H = 1.0f / 511.0f;
        float a4 = W1[4 * HID + t], a5 = W1[5 * HID + t];
        float b  = b1[t];
        LWH w;
        w.a0 = h2c(W1[0 * HID + t]); w.a1 = h2c(W1[1 * HID + t]);
        w.a2 = h2c(W1[2 * HID + t]); w.a3 = h2c(W1[3 * HID + t]);
        w.kLR = h2p(b - H * a4, b + H * a4);  // from left / from right
        w.kUD = h2p(b - H * a5, b + H * a5);  // from up / from down
        w.c0 = h2c(cscale * W2[2 * t + 0]);
        w.c1 = h2c(cscale * W2[2 * t + 1]);
        const int slot = ((t & (JPT - 1)) * SPLIT) | (t / JPT);
        lw[slot] = w;
    }
}

// Kernel 1: grad_u, grad_v, grad_p (UNDAMPED -> lambda-Pade[3/2] tanh).
// SoA out: g[0]=gu0 g[1]=gu1 ... g[5]=gp1
__global__ void __launch_bounds__(256) grad3_kernel(
    const float* __restrict__ fields, const float* __restrict__ degrees,
    const float* __restrict__ W1, const float* __restrict__ b1,
    const float* __restrict__ W2, const float* __restrict__ b2,
    float* __restrict__ g)
{
    __shared__ LWH lw[HID];
    fill_lds(lw, LAM, W1, b1, W2, b2);
    __syncthreads();

    const int gid  = blockIdx.x * 256 + threadIdx.x;
    const int idx  = gid >> 2;          // node (4 lanes per node)
    const int part = gid & 3;           // hidden-dim slice
    const int row = idx >> 9, col = idx & (GW - 1);
    const bool vE0 = col > 0, vE1 = col < GW - 1, vE2 = row > 0, vE3 = row < GW - 1;
    int nb[4];
    nb[0] = vE0 ? idx - 1  : idx;
    nb[1] = vE1 ? idx + 1  : idx;
    nb[2] = vE2 ? idx - GW : idx;
    nb[3] = vE3 ? idx + GW : idx;

    // Pade[3/2] constants
    const h2 cP = h2c(3.4f), cM = h2c(-3.4f), c27 = h2c(27.f), c9 = h2c(9.f),
             two = h2c(2.f);

    h2 s0h[3];
    #pragma unroll
    for (int f = 0; f < 3; ++f) s0h[f] = h2c(fields[3 * idx + f]);
    h2 sN2[2][3];                       // [pair LR/UD][field]
    #pragma unroll
    for (int f = 0; f < 3; ++f) {
        sN2[0][f] = h2p(fields[3 * nb[0] + f], fields[3 * nb[1] + f]);
        sN2[1][f] = h2p(fields[3 * nb[2] + f], fields[3 * nb[3] + f]);
    }
    h2 dnbLR = h2p(degrees[nb[0]], degrees[nb[1]]);
    h2 dnbUD = h2p(degrees[nb[2]], degrees[nb[3]]);
    const float dN = degrees[idx];
    const h2 dNh = h2c(dN);

    h2 acc[2][3][2];                    // [pair][field][W2 comp], sum c*th
    #pragma unroll
    for (int dp = 0; dp < 2; ++dp)
        #pragma unroll
        for (int f = 0; f < 3; ++f) { acc[dp][f][0] = h2c(0.f); acc[dp][f][1] = h2c(0.f); }

    const LWH* lwp = lw + part;
    #pragma unroll 2
    for (int jj = 0; jj < JPT; ++jj) {
        LWH w = lwp[jj * SPLIT];
        h2 dn1 = pk_mul(dNh, w.a1);
        h2 hb[2];
        hb[0] = pk_fma(dnbLR, w.a3, pk_add(w.kLR, dn1));
        hb[1] = pk_fma(dnbUD, w.a3, pk_add(w.kUD, dn1));
        #pragma unroll
        for (int f = 0; f < 3; ++f) {
            #pragma unroll
            for (int dp = 0; dp < 2; ++dp) {
                h2 hh  = pk_fma(sN2[dp][f], w.a2, pk_fma(s0h[f], w.a0, hb[dp]));
                h2 t   = pk_min(cP, pk_max(cM, hh));
                h2 s   = pk_mul(t, t);
                h2 num = pk_mul(t, pk_add(s, c27));
                h2 den = pk_fma(s, c9, c27);            // in [27,131]: magic-safe
                unsigned int db = __builtin_bit_cast(unsigned int, den);
                h2 r0  = __builtin_bit_cast(h2, 0x77987798u - db);
                h2 rr  = pk_mul(r0, pk_nfma(den, r0, two));   // 1 Newton
                h2 th  = pk_mul(num, rr);
                acc[dp][f][0] = pk_fma(th, w.c0, acc[dp][f][0]);
                acc[dp][f][1] = pk_fma(th, w.c1, acc[dp][f][1]);
            }
        }
    }

    const float rd = __builtin_amdgcn_rcpf(dN);
    const float b20 = b2[0], b21 = b2[1];
    #pragma unroll
    for (int f = 0; f < 3; ++f) {
        #pragma unroll
        for (int c = 0; c < 2; ++c) {
            float s = 0.f;
            s += vE0 ? (float)acc[0][f][c].x : 0.f;
            s += vE1 ? (float)acc[0][f][c].y : 0.f;
            s += vE2 ? (float)acc[1][f][c].x : 0.f;
            s += vE3 ? (float)acc[1][f][c].y : 0.f;
            s += __shfl_xor(s, 1);
            s += __shfl_xor(s, 2);
            if (part == 0)
                g[(2 * f + c) * GN + idx] = __builtin_fmaf(s, rd, c ? b21 : b20);
        }
    }
}

// Kernel 2: second-order g (damped by NU=0.01 -> cubic activation) + combine.
__global__ void __launch_bounds__(256) final_kernel(
    const float* __restrict__ fields, const float* __restrict__ degrees,
    const float* __restrict__ W1, const float* __restrict__ b1,
    const float* __restrict__ W2, const float* __restrict__ b2,
    const float* __restrict__ g, float* __restrict__ out)
{
    __shared__ LWH lw[HID];
    fill_lds(lw, 1.0f, W1, b1, W2, b2);
    __syncthreads();

    const int gid  = blockIdx.x * 256 + threadIdx.x;
    const int idx  = gid >> 2;
    const int part = gid & 3;
    const int row = idx >> 9, col = idx & (GW - 1);
    const bool vE0 = col > 0, vE1 = col < GW - 1, vE2 = row > 0, vE3 = row < GW - 1;
    int nb[4];
    nb[0] = vE0 ? idx - 1  : idx;
    nb[1] = vE1 ? idx + 1  : idx;
    nb[2] = vE2 ? idx - GW : idx;
    nb[3] = vE3 ? idx + GW : idx;

    // cubic tanh: t = clamp(h,+-2); th = t*(0.75 - 0.0625 t^2)
    const h2 cP = h2c(2.0f), cM = h2c(-2.0f), cA = h2c(0.75f), cB = h2c(-0.0625f);

    float s0[4];
    #pragma unroll
    for (int f = 0; f < 4; ++f) s0[f] = g[f * GN + idx];
    h2 s0h[4];
    #pragma unroll
    for (int f = 0; f < 4; ++f) s0h[f] = h2c(s0[f]);
    h2 sN2[2][4];
    #pragma unroll
    for (int f = 0; f < 4; ++f) {
        sN2[0][f] = h2p(g[f * GN + nb[0]], g[f * GN + nb[1]]);
        sN2[1][f] = h2p(g[f * GN + nb[2]], g[f * GN + nb[3]]);
    }
    h2 dnbLR = h2p(degrees[nb[0]], degrees[nb[1]]);
    h2 dnbUD = h2p(degrees[nb[2]], degrees[nb[3]]);
    const float dN = degrees[idx];
    const h2 dNh = h2c(dN);

    h2 acc[2][4];                       // [pair][field], sum c*th
    #pragma unroll
    for (int dp = 0; dp < 2; ++dp)
        #pragma unroll
        for (int f = 0; f < 4; ++f) acc[dp][f] = h2c(0.f);

    const LWH* lwp = lw + part;
    #pragma unroll 2
    for (int jj = 0; jj < JPT; ++jj) {
        LWH w = lwp[jj * SPLIT];
        h2 dn1 = pk_mul(dNh, w.a1);
        h2 hb[2];
        hb[0] = pk_fma(dnbLR, w.a3, pk_add(w.kLR, dn1));
        hb[1] = pk_fma(dnbUD, w.a3, pk_add(w.kUD, dn1));
        #pragma unroll
        for (int f = 0; f < 4; ++f) {
            h2 cc = (f & 1) ? w.c1 : w.c0;   // needed comp: 0,1,0,1
            #pragma unroll
            for (int dp = 0; dp < 2; ++dp) {
                h2 hh = pk_fma(sN2[dp][f], w.a2, pk_fma(s0h[f], w.a0, hb[dp]));
                h2 t  = pk_min(cP, pk_max(cM, hh));
                h2 th = pk_mul(t, pk_fma(pk_mul(t, t), cB, cA));
                acc[dp][f] = pk_fma(th, cc, acc[dp][f]);
            }
        }
    }

    const float rd = __builtin_amdgcn_rcpf(dN);
    float r[4];
    #pragma unroll
    for (int f = 0; f < 4; ++f) {
        float s = 0.f;
        s += vE0 ? (float)acc[0][f].x : 0.f;
        s += vE1 ? (float)acc[0][f].y : 0.f;
        s += vE2 ? (float)acc[1][f].x : 0.f;
        s += vE3 ? (float)acc[1][f].y : 0.f;
        s += __shfl_xor(s, 1);
        s += __shfl_xor(s, 2);
        r[f] = __builtin_fmaf(s, rd, b2[f & 1]);
    }

    if (part == 0) {
        const float lap_u = r[0] + r[1];   // grad_ux[:,0] + grad_uy[:,1]
        const float lap_v = r[2] + r[3];   // grad_vx[:,0] + grad_vy[:,1]
        const float u = fields[3 * idx + 0], v = fields[3 * idx + 1];
        const float gu0 = s0[0], gu1 = s0[1], gv0 = s0[2], gv1 = s0[3];
        const float gp0 = g[4 * GN + idx], gp1 = g[5 * GN + idx];
        out[3 * idx + 0] = gu0 + gv1;                                // continuity
        out[3 * idx + 1] = u * gu0 + v * gu1 + gp0 - NUC * lap_u;    // mom_x
        out[3 * idx + 2] = u * gv0 + v * gv1 + gp1 - NUC * lap_v;    // mom_y
    }
}

extern "C" void kernel_launch(void* const* d_in, const int* in_sizes, int n_in,
                              void* d_out, int out_size, void* d_ws, size_t ws_size,
                              hipStream_t stream) {
    const float* fields  = (const float*)d_in[0];
    const float* degrees = (const float*)d_in[1];
    const float* W1 = (const float*)d_in[3];
    const float* b1 = (const float*)d_in[4];
    const float* W2 = (const float*)d_in[5];
    const float* b2 = (const float*)d_in[6];
    float* g   = (float*)d_ws;           // 6 * GN floats = 6.3 MB scratch
    float* out = (float*)d_out;

    const int blocks = (GN * SPLIT) / 256;   // 4096
    grad3_kernel<<<blocks, 256, 0, stream>>>(fields, degrees, W1, b1, W2, b2, g);
    final_kernel<<<blocks, 256, 0, stream>>>(fields, degrees, W1, b1, W2, b2, g, out);
}